// Round 1
// baseline (795.833 us; speedup 1.0000x reference)
//
#include <hip/hip_runtime.h>
#include <hip/hip_bf16.h>

#define BATCH 32
#define CIN   64
#define COUT  128
#define HIN   128
#define WIN   128
#define HOUT  64
#define WOUT  64

// ---------------- Kernel 1: Gabor filters (O*I threads) ----------------
__global__ __launch_bounds__(256) void gabor_filters_kernel(
    const float* __restrict__ freq, const float* __restrict__ theta,
    const float* __restrict__ psi,  const float* __restrict__ sigma,
    float* __restrict__ w, int n) {
  int idx = blockIdx.x * blockDim.x + threadIdx.x;
  if (idx >= n) return;
  float f = freq[idx], t = theta[idx], p = psi[idx], s = sigma[idx];
  float ct = cosf(t), st = sinf(t);
  float se = s + 0.001f;
  float gscale = -0.5f / (se * se);
  float norm = 1.0f / (2.0f * 3.14f * s * s);   // PI = 3.14 in the reference!
  const float lin[4] = {-1.f, 0.f, 1.f, 2.f};   // linspace(-1, 2, 4)
  #pragma unroll
  for (int ky = 0; ky < 4; ++ky) {
    #pragma unroll
    for (int kx = 0; kx < 4; ++kx) {
      float x = lin[kx], y = lin[ky];
      float rotx =  x * ct + y * st;
      float roty = -x * st + y * ct;
      float g = __expf(gscale * (rotx * rotx + roty * roty));
      g *= cosf(f * rotx + p) * norm;
      w[idx * 16 + ky * 4 + kx] = g;
    }
  }
}

// ---------------- Kernel 2: direct conv, fp32 ----------------
// block: 256 threads = 16x16 output spatial tile; OT=16 output channels/block
// grid: (16 spatial tiles, COUT/16=8, BATCH=32)
constexpr int OT = 16;
constexpr int XT_H = 35, XT_W = 35, XT_P = 36;  // input tile + halo, padded pitch

__global__ __launch_bounds__(256) void conv_kernel(
    const float* __restrict__ x, const float* __restrict__ w,
    float* __restrict__ out, float2* __restrict__ part) {
  __shared__ float xt[XT_H * XT_P];
  __shared__ float wsum[OT][4], wsq[OT][4];

  const int tid = threadIdx.x;
  const int sp  = blockIdx.x;            // 0..15
  const int ohb = (sp >> 2) * 16;
  const int owb = (sp & 3) * 16;
  const int o0  = blockIdx.y * OT;
  const int b   = blockIdx.z;
  const int ty  = tid >> 4, tx = tid & 15;
  const int oh  = ohb + ty, ow = owb + tx;
  const int ihb = ohb * 2 - 1, iwb = owb * 2 - 1;

  float acc[OT];
  #pragma unroll
  for (int o = 0; o < OT; ++o) acc[o] = 0.f;

  for (int i = 0; i < CIN; ++i) {
    const float* __restrict__ xp = x + ((size_t)(b * CIN + i)) * (HIN * WIN);
    __syncthreads();   // protect previous iteration's reads
    for (int s = tid; s < XT_H * XT_W; s += 256) {
      int ly = s / XT_W, lx = s - ly * XT_W;
      int ih = ihb + ly, iw = iwb + lx;
      float v = 0.f;
      if ((unsigned)ih < HIN && (unsigned)iw < WIN) v = xp[ih * WIN + iw];
      xt[ly * XT_P + lx] = v;
    }
    __syncthreads();

    float patch[16];
    #pragma unroll
    for (int kh = 0; kh < 4; ++kh)
      #pragma unroll
      for (int kw = 0; kw < 4; ++kw)
        patch[kh * 4 + kw] = xt[(ty * 2 + kh) * XT_P + (tx * 2 + kw)];

    // block-uniform filter pointers -> scalar (SGPR) loads
    const float* __restrict__ wp = w + ((size_t)o0 * CIN + i) * 16;
    #pragma unroll
    for (int o = 0; o < OT; ++o) {
      const float* __restrict__ wo = wp + (size_t)o * CIN * 16;
      float a = acc[o];
      #pragma unroll
      for (int k = 0; k < 16; ++k) a = fmaf(patch[k], wo[k], a);
      acc[o] = a;
    }
  }

  // write conv output
  #pragma unroll
  for (int o = 0; o < OT; ++o)
    out[(((size_t)b * COUT + (o0 + o)) * HOUT + oh) * WOUT + ow] = acc[o];

  // deterministic per-block partial sums (sum, sumsq) per channel
  const int lane = tid & 63, wv = tid >> 6;
  #pragma unroll
  for (int o = 0; o < OT; ++o) {
    float s1 = acc[o];
    float s2 = acc[o] * acc[o];
    #pragma unroll
    for (int off = 32; off > 0; off >>= 1) {
      s1 += __shfl_down(s1, off);
      s2 += __shfl_down(s2, off);
    }
    if (lane == 0) { wsum[o][wv] = s1; wsq[o][wv] = s2; }
  }
  __syncthreads();
  if (tid < OT) {
    float s1 = wsum[tid][0] + wsum[tid][1] + wsum[tid][2] + wsum[tid][3];
    float s2 = wsq[tid][0] + wsq[tid][1] + wsq[tid][2] + wsq[tid][3];
    int blk = b * 16 + sp;                 // 0..511 blocks per channel
    part[(size_t)(o0 + tid) * 512 + blk] = make_float2(s1, s2);
  }
}

// ---------------- Kernel 3: per-channel stats -> (a,b) ----------------
__global__ __launch_bounds__(256) void stats_kernel(
    const float2* __restrict__ part, const float* __restrict__ gamma,
    const float* __restrict__ beta, float2* __restrict__ ab) {
  int o = blockIdx.x;
  int tid = threadIdx.x;
  float s1 = 0.f, s2 = 0.f;
  #pragma unroll
  for (int t = 0; t < 2; ++t) {
    float2 p = part[(size_t)o * 512 + tid + t * 256];
    s1 += p.x; s2 += p.y;
  }
  __shared__ float r1[256], r2[256];
  r1[tid] = s1; r2[tid] = s2;
  __syncthreads();
  for (int off = 128; off > 0; off >>= 1) {
    if (tid < off) { r1[tid] += r1[tid + off]; r2[tid] += r2[tid + off]; }
    __syncthreads();
  }
  if (tid == 0) {
    const float N = (float)BATCH * HOUT * WOUT;  // 131072
    float mean = r1[0] / N;
    float var  = r2[0] / N - mean * mean;
    float inv  = rsqrtf(var + 1e-5f);
    float a = gamma[o] * inv;
    float bb = beta[o] - mean * a;
    ab[o] = make_float2(a, bb);
  }
}

// ---------------- Kernel 4: normalize + leaky ReLU (in-place, float4) ----------------
__global__ __launch_bounds__(256) void norm_kernel(
    float* __restrict__ out, const float2* __restrict__ ab) {
  size_t idx = (size_t)blockIdx.x * 256 + threadIdx.x;  // float4 index
  int o = (int)((idx >> 10) & (COUT - 1));              // 1024 float4 per (b,o) plane
  float2 s = ab[o];
  float4 v = reinterpret_cast<float4*>(out)[idx];
  v.x = fmaf(v.x, s.x, s.y);
  v.y = fmaf(v.y, s.x, s.y);
  v.z = fmaf(v.z, s.x, s.y);
  v.w = fmaf(v.w, s.x, s.y);
  v.x = v.x >= 0.f ? v.x : 0.1f * v.x;
  v.y = v.y >= 0.f ? v.y : 0.1f * v.y;
  v.z = v.z >= 0.f ? v.z : 0.1f * v.z;
  v.w = v.w >= 0.f ? v.w : 0.1f * v.w;
  reinterpret_cast<float4*>(out)[idx] = v;
}

extern "C" void kernel_launch(void* const* d_in, const int* in_sizes, int n_in,
                              void* d_out, int out_size, void* d_ws, size_t ws_size,
                              hipStream_t stream) {
  const float* x     = (const float*)d_in[0];
  const float* freq  = (const float*)d_in[1];
  const float* theta = (const float*)d_in[2];
  const float* psi   = (const float*)d_in[3];
  const float* sigma = (const float*)d_in[4];
  const float* gamma = (const float*)d_in[5];
  const float* beta  = (const float*)d_in[6];
  float* out = (float*)d_out;

  // workspace layout
  float*  w    = (float*)d_ws;                                    // 512 KiB
  float2* part = (float2*)((char*)d_ws + (512 << 10));            // 512 KiB
  float2* ab   = (float2*)((char*)d_ws + (1024 << 10));           // 1 KiB

  const int nfilt = COUT * CIN;  // 8192
  gabor_filters_kernel<<<nfilt / 256, 256, 0, stream>>>(freq, theta, psi, sigma, w, nfilt);
  conv_kernel<<<dim3(16, COUT / OT, BATCH), 256, 0, stream>>>(x, w, out, part);
  stats_kernel<<<COUT, 256, 0, stream>>>(part, gamma, beta, ab);
  // out_size = 32*128*64*64 = 16777216 -> 4194304 float4
  norm_kernel<<<4194304 / 256, 256, 0, stream>>>(out, ab);
}

// Round 5
// 142.921 us; speedup vs baseline: 5.5683x; 5.5683x over previous
//
#include <hip/hip_runtime.h>
#include <hip/hip_bf16.h>

#define BATCH 32
#define CIN   64
#define COUT  128
#define HIN   128
#define WIN   128
#define HOUT  64
#define WOUT  64

typedef unsigned int u32;
typedef __attribute__((ext_vector_type(8))) short short8;
typedef __attribute__((ext_vector_type(4))) float f32x4;

// ---------------- ws layout ----------------
// wsW  : byte      0 .. 262144 : bf16 weights, linear [16 chunks][128 o][64 k6]
// part : byte 262144 .. 786432 : [128][512] float2 partial sums
// ab   : byte 786432 .. 787456 : [128] float2 (scale, shift)

__device__ inline unsigned short f2bf(float v) {
  __hip_bfloat16 h = __float2bfloat16(v);
  return *reinterpret_cast<unsigned short*>(&h);
}
__device__ inline u32 pack2(float a, float b) {
  return (u32)f2bf(a) | ((u32)f2bf(b) << 16);
}

// ---------------- Kernel 1: Gabor filters -> linear bf16 ----------------
// k = i*16 + kh*4 + kw ; chunk c = i>>2 ; k6 = (i&3)*16 + kh*4 + kw
// wsW[(c*128 + o)*64 + k6]
__global__ __launch_bounds__(256) void gabor_kernel(
    const float* __restrict__ freq, const float* __restrict__ theta,
    const float* __restrict__ psi,  const float* __restrict__ sigma,
    __hip_bfloat16* __restrict__ wsw) {
  int idx = blockIdx.x * 256 + threadIdx.x;     // 8192 = 128*64
  int o = idx >> 6, i = idx & 63;
  float f = freq[idx], t = theta[idx], p = psi[idx], s = sigma[idx];
  float ct = cosf(t), st = sinf(t);
  float se = s + 0.001f;
  float gsc = -0.5f / (se * se);
  float nrm = 1.0f / (2.0f * 3.14f * s * s);    // PI = 3.14 in the reference
  const float lin[4] = {-1.f, 0.f, 1.f, 2.f};
  int chunk = i >> 2;
  #pragma unroll
  for (int ky = 0; ky < 4; ++ky) {
    #pragma unroll
    for (int kx = 0; kx < 4; ++kx) {
      float xx = lin[kx], yy = lin[ky];
      float rx =  xx * ct + yy * st;
      float ry = -xx * st + yy * ct;
      float g = __expf(gsc * (rx * rx + ry * ry)) * cosf(f * rx + p) * nrm;
      int k6 = (i & 3) * 16 + ky * 4 + kx;
      wsw[((size_t)(chunk * 128 + o)) * 64 + k6] = __float2bfloat16(g);
    }
  }
}

// ---------------- Kernel 2: implicit-GEMM conv via MFMA ----------------
// Block: 256 thr (4 waves, 2x2 split). Tile M=128 (all COUT) x N=256 (4 oh x 64 ow).
// K loop: 16 chunks of 64 (4 input channels each). X double buffered in LDS;
// A fragments loaded straight from global (L2-resident 256 KiB).
constexpr int XPITCH = 70;    // dwords per x-tile row (140 bf16; ci = iw+3)
constexpr int XCH    = 700;   // dwords per channel plane (10 rows)
constexpr int XBYTES = 11200; // 4 ch * 700 dw * 4 B
constexpr int NSLOT  = 1360;  // 4 ch * 10 rows * 34 quads

__global__ __launch_bounds__(256, 2) void conv_mfma(
    const float* __restrict__ x, const char* __restrict__ wsW,
    float* __restrict__ out, float2* __restrict__ part) {
  __shared__ __align__(16) char lds[2 * XBYTES];

  const int tid = threadIdx.x;
  const int l = tid & 63, w = tid >> 6;
  const int wm = w & 1, wn = w >> 1;
  const int t4 = l >> 4, lcol = l & 15;
  const int khp = t4 & 1, ihalf = t4 >> 1;
  const int ohb = blockIdx.x, b = blockIdx.y;
  const int oh0 = ohb * 4;

  // ---- staging precompute: 6 slots/thread, sg = tid + u*256 (covers 0..1535 >= 1360) ----
  bool act[6]; int xdw[6]; const float* gp[6]; int vmask[6];
  #pragma unroll
  for (int u = 0; u < 6; ++u) {
    int sg = tid + u * 256;
    act[u] = sg < NSLOT;
    int r = sg / 34, s = sg - r * 34;      // quad s: cols 4s..4s+3 (iw = col-3)
    int ch = r / 10, row = r - ch * 10;
    int ih = oh0 * 2 - 1 + row;
    bool rok = act[u] && ((unsigned)ih < 128u);
    xdw[u] = ch * XCH + row * XPITCH + s * 2;
    gp[u] = x + (((size_t)(b * 64 + ch) << 14) + (size_t)ih * 128 + (4 * s - 3));
    int m = 0;
    #pragma unroll
    for (int e = 0; e < 4; ++e)
      if (rok && ((unsigned)(4 * s - 3 + e) < 128u)) m |= (1 << e);
    vmask[u] = m;
  }

  uint2 pk[6];
  auto XLOAD = [&](int c) {
    #pragma unroll
    for (int u = 0; u < 6; ++u) {
      const float* p = gp[u] + (size_t)c * 65536;    // 4 channels * 16384 floats
      float a0 = (vmask[u] & 1) ? p[0] : 0.f;
      float a1 = (vmask[u] & 2) ? p[1] : 0.f;
      float a2 = (vmask[u] & 4) ? p[2] : 0.f;
      float a3 = (vmask[u] & 8) ? p[3] : 0.f;
      pk[u].x = pack2(a0, a1);
      pk[u].y = pack2(a2, a3);
    }
  };
  auto XWRITE = [&](int nb) {
    u32* X = (u32*)(lds + nb * XBYTES);
    #pragma unroll
    for (int u = 0; u < 6; ++u)
      if (act[u]) *(uint2*)(X + xdw[u]) = pk[u];
  };

  f32x4 acc[4][8];
  #pragma unroll
  for (int mf = 0; mf < 4; ++mf)
    #pragma unroll
    for (int nf = 0; nf < 8; ++nf) acc[mf][nf] = {0.f, 0.f, 0.f, 0.f};

  // B-fragment dword offsets (within X buffer)
  int bo[8];
  #pragma unroll
  for (int nf = 0; nf < 8; ++nf) {
    int nfb = 8 * wn + nf;
    bo[nf] = ihalf * XCH + khp * (2 * XPITCH) + lcol + 1 +
             (nfb >> 2) * (2 * XPITCH) + ((nfb & 3) << 4);
  }

  // A-fragment per-lane global base: row o = wm*64 + mf*16 + lcol, k6 = kk*32 + t4*8 + j
  const char* wl = wsW + wm * 8192 + lcol * 128 + t4 * 16;

  auto COMPUTE = [&](int c, int cb) {
    const char* wc = wl + c * 16384;
    const u32* Xb = (const u32*)(lds + cb * XBYTES);
    #pragma unroll
    for (int kk = 0; kk < 2; ++kk) {
      short8 af[4];
      #pragma unroll
      for (int mf = 0; mf < 4; ++mf)
        af[mf] = *(const short8*)(wc + mf * 2048 + kk * 64);
      #pragma unroll
      for (int nf = 0; nf < 8; ++nf) {
        const u32* p = Xb + bo[nf] + kk * 1400;      // 2 channel planes
        union { u32 u[4]; short8 s8; } bu;
        bu.u[0] = p[0]; bu.u[1] = p[1];
        bu.u[2] = p[XPITCH]; bu.u[3] = p[XPITCH + 1];
        short8 bf = bu.s8;
        #pragma unroll
        for (int mf = 0; mf < 4; ++mf)
          acc[mf][nf] = __builtin_amdgcn_mfma_f32_16x16x32_bf16(af[mf], bf, acc[mf][nf], 0, 0, 0);
      }
    }
  };

  // ---- main loop: X double-buffered, A straight from global ----
  XLOAD(0); XWRITE(0);
  __syncthreads();
  for (int c = 0; c < 16; ++c) {
    int cur = c & 1;
    if (c < 15) XLOAD(c + 1);
    COMPUTE(c, cur);
    if (c < 15) XWRITE(cur ^ 1);
    __syncthreads();
  }

  // ---- epilogue: conv output (C/D layout: col=lane&15, row=(lane>>4)*4+reg) ----
  size_t obase = ((size_t)b * 128) * 4096;
  #pragma unroll
  for (int mf = 0; mf < 4; ++mf)
    #pragma unroll
    for (int nf = 0; nf < 8; ++nf) {
      int nfb = 8 * wn + nf;
      int oh = oh0 + (nfb >> 2), ow = ((nfb & 3) << 4) + lcol;
      #pragma unroll
      for (int r = 0; r < 4; ++r) {
        int o = wm * 64 + mf * 16 + t4 * 4 + r;
        out[obase + (size_t)o * 4096 + oh * 64 + ow] = acc[mf][nf][r];
      }
    }

  // ---- deterministic per-block (sum, sumsq) partials ----
  float* ps = (float*)lds;    // reuse LDS: [128][2 wn][2] floats
  #pragma unroll
  for (int mf = 0; mf < 4; ++mf)
    #pragma unroll
    for (int r = 0; r < 4; ++r) {
      float s1 = 0.f, s2 = 0.f;
      #pragma unroll
      for (int nf = 0; nf < 8; ++nf) { float v = acc[mf][nf][r]; s1 += v; s2 += v * v; }
      #pragma unroll
      for (int d = 1; d < 16; d <<= 1) { s1 += __shfl_xor(s1, d); s2 += __shfl_xor(s2, d); }
      if (lcol == 0) {
        int o = wm * 64 + mf * 16 + t4 * 4 + r;
        ps[o * 4 + wn * 2 + 0] = s1;
        ps[o * 4 + wn * 2 + 1] = s2;
      }
    }
  __syncthreads();
  if (tid < 128) {
    float s1 = ps[tid * 4 + 0] + ps[tid * 4 + 2];
    float s2 = ps[tid * 4 + 1] + ps[tid * 4 + 3];
    part[(size_t)tid * 512 + b * 16 + ohb] = make_float2(s1, s2);
  }
}

// ---------------- Kernel 3: per-channel stats -> (a,b) ----------------
__global__ __launch_bounds__(256) void stats_kernel(
    const float2* __restrict__ part, const float* __restrict__ gamma,
    const float* __restrict__ beta, float2* __restrict__ ab) {
  int o = blockIdx.x;
  int tid = threadIdx.x;
  float s1 = 0.f, s2 = 0.f;
  #pragma unroll
  for (int t = 0; t < 2; ++t) {
    float2 p = part[(size_t)o * 512 + tid + t * 256];
    s1 += p.x; s2 += p.y;
  }
  __shared__ float r1[256], r2[256];
  r1[tid] = s1; r2[tid] = s2;
  __syncthreads();
  for (int off = 128; off > 0; off >>= 1) {
    if (tid < off) { r1[tid] += r1[tid + off]; r2[tid] += r2[tid + off]; }
    __syncthreads();
  }
  if (tid == 0) {
    const float N = (float)BATCH * HOUT * WOUT;   // 131072
    float mean = r1[0] / N;
    float var  = r2[0] / N - mean * mean;
    float inv  = rsqrtf(var + 1e-5f);
    float a = gamma[o] * inv;
    float bb = beta[o] - mean * a;
    ab[o] = make_float2(a, bb);
  }
}

// ---------------- Kernel 4: normalize + leaky ReLU (in-place, float4) ----------------
__global__ __launch_bounds__(256) void norm_kernel(
    float* __restrict__ out, const float2* __restrict__ ab) {
  size_t idx = (size_t)blockIdx.x * 256 + threadIdx.x;   // float4 index
  int o = (int)((idx >> 10) & (COUT - 1));               // 1024 float4 per (b,o) plane
  float2 s = ab[o];
  float4 v = reinterpret_cast<float4*>(out)[idx];
  v.x = fmaf(v.x, s.x, s.y);
  v.y = fmaf(v.y, s.x, s.y);
  v.z = fmaf(v.z, s.x, s.y);
  v.w = fmaf(v.w, s.x, s.y);
  v.x = v.x >= 0.f ? v.x : 0.1f * v.x;
  v.y = v.y >= 0.f ? v.y : 0.1f * v.y;
  v.z = v.z >= 0.f ? v.z : 0.1f * v.z;
  v.w = v.w >= 0.f ? v.w : 0.1f * v.w;
  reinterpret_cast<float4*>(out)[idx] = v;
}

extern "C" void kernel_launch(void* const* d_in, const int* in_sizes, int n_in,
                              void* d_out, int out_size, void* d_ws, size_t ws_size,
                              hipStream_t stream) {
  const float* x     = (const float*)d_in[0];
  const float* freq  = (const float*)d_in[1];
  const float* theta = (const float*)d_in[2];
  const float* psi   = (const float*)d_in[3];
  const float* sigma = (const float*)d_in[4];
  const float* gamma = (const float*)d_in[5];
  const float* beta  = (const float*)d_in[6];
  float* out = (float*)d_out;

  __hip_bfloat16* wsw = (__hip_bfloat16*)d_ws;
  float2* part = (float2*)((char*)d_ws + 262144);
  float2* ab   = (float2*)((char*)d_ws + 786432);

  gabor_kernel<<<32, 256, 0, stream>>>(freq, theta, psi, sigma, wsw);
  conv_mfma<<<dim3(16, BATCH), 256, 0, stream>>>(x, (const char*)d_ws, out, part);
  stats_kernel<<<COUT, 256, 0, stream>>>(part, gamma, beta, ab);
  norm_kernel<<<4194304 / 256, 256, 0, stream>>>(out, ab);
}